// Round 9
// baseline (395.664 us; speedup 1.0000x reference)
//
#include <hip/hip_runtime.h>
#include <math.h>

// Problem constants
constexpr int BB   = 8;      // mamba batch (2x half-batch)
constexpr int HB   = 4;      // half batch
constexpr int LSEQ = 2048;   // sequence length
constexpr int DMv  = 64;     // d_model
constexpr int DIv  = 128;    // d_inner
constexpr int DSv  = 16;     // d_state
constexpr int DRv  = 4;      // dt rank
constexpr int KCv  = 4;      // conv kernel
constexpr int NPOS = BB * LSEQ;          // 16384 positions
constexpr int CH   = 8;                  // scan chunk length
constexpr int NCH  = LSEQ / CH;          // 256 chunks
constexpr int NLANE = BB * DIv * DSv;    // 16384 scan lanes
constexpr int NROW = CH + 3;             // 11 rows incl. conv halo

#define DEV static __device__ __forceinline__

DEV float fast_rcp(float v) { return __builtin_amdgcn_rcpf(v); }
DEV float siluf(float v) { return v * fast_rcp(1.0f + __expf(-v)); }
DEV float softplusf(float v) { return (v > 20.0f) ? v : __logf(1.0f + __expf(v)); }

// ---------------- weight repack (once per call) ----------------
__global__ void k_transpose(const float* __restrict__ Aa, const float* __restrict__ Ab,
                            int R, int C, float* __restrict__ dst) {
    int z = blockIdx.z;
    const float* src = (z < 2) ? (Aa + (size_t)z * R * C) : (Ab + (size_t)(z - 2) * R * C);
    float* d = dst + (size_t)z * R * C;
    int idx = blockIdx.x * blockDim.x + threadIdx.x;
    if (idx >= R * C) return;
    int r = idx / C, c = idx % C;
    d[c * R + r] = src[idx];
}

// quad-pack: src[e*K + k] -> dst[((k>>2)*E + e)*4 + (k&3)]
__global__ void k_quadpack(const float* __restrict__ Aa, const float* __restrict__ Ab,
                           int E, int K, float* __restrict__ dst) {
    int z = blockIdx.z;
    const float* src = (z < 2) ? (Aa + (size_t)z * E * K) : (Ab + (size_t)(z - 2) * E * K);
    float* d = dst + (size_t)z * E * K;
    int idx = blockIdx.x * blockDim.x + threadIdx.x;
    if (idx >= E * K) return;
    int e = idx / K, k = idx % K;
    d[((size_t)(k >> 2) * E + e) * 4 + (k & 3)] = src[idx];
}

// ================= fused front =================================================
// in-proj(+gather) + conv + x-proj + scan pass 1. grid (BB, NCH), block 256.
// Phase 1 q-outer: thread = output col e (0..255), acc[NROW] rows, one w-quad live.
// MODE 0: rows from S1. MODE 1: prep_a gather. MODE 2: prep_b gather.
template<int MODE>
__global__ __launch_bounds__(256, 8) void k_front(
    const float* __restrict__ S1, const float* __restrict__ S2,
    const float* __restrict__ WQ,          // in_w quad-packed [16][256]xfloat4
    const float* __restrict__ conv_w, const float* __restrict__ conv_b,
    const float* __restrict__ XPWT,        // xp_w^T [128][36]
    const float* __restrict__ A_log, const float* __restrict__ dt_w,
    const float* __restrict__ dt_b,
    float* __restrict__ XA_g, float* __restrict__ SZ_g, float* __restrict__ XD_g,
    float* __restrict__ Pc, float* __restrict__ Sc)
{
    // LDS: lds_x [11][128] (x rows; rows 0..7 reused as xa); lds_xd [8][36]; lds_w [128][36]
    __shared__ float smem[NROW * 128 + CH * 36 + DIv * 36];
    float* lds_x  = smem;
    float* lds_xd = smem + NROW * 128;
    float* lds_w  = smem + NROW * 128 + CH * 36;

    const int t  = threadIdx.x;
    const int b8 = blockIdx.x, ch = blockIdx.y;
    const int c0 = ch * CH;

    // stage xp_w^T into LDS (no phase-1 consumer; covered by sync #1)
    for (int f = t; f < DIv * 36; f += 256) lds_w[f] = XPWT[f];

    // ---- phase 1: in-proj GEMV, q-outer, acc[NROW] ----
    {
        const float* rows[NROW];
#pragma unroll
        for (int i = 0; i < NROW; ++i) {
            int c = c0 - 3 + i;
            if (c < 0) { rows[i] = nullptr; continue; }
            if (MODE == 0) {
                rows[i] = S1 + ((size_t)b8 * LSEQ + c) * DMv;
            } else {
                int b = b8 & 3;
                bool first = (MODE == 1) ? (c < (LSEQ / 2)) : ((c & 1) == 0);
                const float* sel;
                if (MODE == 1) sel = (b8 < HB) ? (first ? S1 : S2) : (first ? S2 : S1);
                else           sel = (b8 < HB) ? (first ? S2 : S1) : (first ? S1 : S2);
                rows[i] = sel + ((size_t)b * LSEQ + c) * DMv;
            }
        }
        float acc[NROW];
#pragma unroll
        for (int i = 0; i < NROW; ++i) acc[i] = 0.f;
        const float4* wq4 = (const float4*)WQ;
#pragma unroll
        for (int q = 0; q < DMv / 4; ++q) {
            float4 wv = wq4[q * 256 + t];
#pragma unroll
            for (int i = 0; i < NROW; ++i) {
                if (rows[i]) {
                    float4 v = ((const float4*)rows[i])[q];
                    acc[i] = fmaf(v.x, wv.x, acc[i]);
                    acc[i] = fmaf(v.y, wv.y, acc[i]);
                    acc[i] = fmaf(v.z, wv.z, acc[i]);
                    acc[i] = fmaf(v.w, wv.w, acc[i]);
                }
            }
        }
        if (t < DIv) {
#pragma unroll
            for (int i = 0; i < NROW; ++i) lds_x[i * 128 + t] = acc[i];
        } else {
#pragma unroll
            for (int i = 3; i < NROW; ++i)
                SZ_g[((size_t)b8 * LSEQ + (c0 - 3 + i)) * DIv + (t - DIv)] = siluf(acc[i]);
        }
    }
    __syncthreads();

    // ---- phase 2a: causal conv (K=4) + silu into regs ----
    float xar[4];
    {
        const int d = t & 127;
        const int lb = t >> 7;   // 0/1
        float4 cw4 = ((const float4*)conv_w)[d];
        float cb = conv_b[d];
#pragma unroll
        for (int j = 0; j < 4; ++j) {
            int l = lb * 4 + j;
            float a = cb;
            a = fmaf(cw4.x, lds_x[(l + 0) * 128 + d], a);
            a = fmaf(cw4.y, lds_x[(l + 1) * 128 + d], a);
            a = fmaf(cw4.z, lds_x[(l + 2) * 128 + d], a);
            a = fmaf(cw4.w, lds_x[(l + 3) * 128 + d], a);
            float v = siluf(a);
            xar[j] = v;
            XA_g[((size_t)b8 * LSEQ + c0 + l) * DIv + d] = v;
        }
    }
    __syncthreads();
    // ---- phase 2b: write xa into lds_x rows 0..7 (x rows dead) ----
    {
        const int d = t & 127;
        const int lb = t >> 7;
#pragma unroll
        for (int j = 0; j < 4; ++j) lds_x[(lb * 4 + j) * 128 + d] = xar[j];
    }
    __syncthreads();

    // ---- phase 3: x-proj (36 outputs per position) ----
    for (int f = t; f < CH * 36; f += 256) {
        int l = f / 36, e = f % 36;
        const float* x = lds_x + l * 128;
        float a0 = 0.f, a1 = 0.f;
#pragma unroll
        for (int k = 0; k < DIv; k += 2) {
            a0 = fmaf(x[k],     lds_w[k * 36 + e],       a0);
            a1 = fmaf(x[k + 1], lds_w[(k + 1) * 36 + e], a1);
        }
        float v = a0 + a1;
        lds_xd[f] = v;
        XD_g[((size_t)b8 * LSEQ + c0) * 36 + f] = v;
    }
    __syncthreads();

    // ---- phase 4: scan pass 1 (thread = (d, s-half), 8 states in regs) ----
    {
        int d = t & 127, sh = t >> 7;
        float A[8], h[8], P[8];
#pragma unroll
        for (int s = 0; s < 8; ++s) {
            A[s] = -__expf(A_log[d * DSv + sh * 8 + s]);
            h[s] = 0.f; P[s] = 1.f;
        }
        float4 dw4 = ((const float4*)dt_w)[d];
        float bb = dt_b[d];
#pragma unroll
        for (int l = 0; l < CH; ++l) {
            const float* xd = lds_xd + l * 36;
            float delta = softplusf(fmaf(xd[0], dw4.x, fmaf(xd[1], dw4.y,
                                   fmaf(xd[2], dw4.z, fmaf(xd[3], dw4.w, bb)))));
            float dx = delta * lds_x[l * 128 + d];
#pragma unroll
            for (int s = 0; s < 8; ++s) {
                float dA = __expf(delta * A[s]);
                h[s] = fmaf(dA, h[s], dx * xd[DRv + sh * 8 + s]);
                P[s] *= dA;
            }
        }
        size_t ofs = (size_t)ch * NLANE + ((size_t)b8 * DIv + d) * DSv + sh * 8;
        float4* p4 = (float4*)(Pc + ofs);
        float4* s4 = (float4*)(Sc + ofs);
        p4[0] = make_float4(P[0], P[1], P[2], P[3]);
        p4[1] = make_float4(P[4], P[5], P[6], P[7]);
        s4[0] = make_float4(h[0], h[1], h[2], h[3]);
        s4[1] = make_float4(h[4], h[5], h[6], h[7]);
    }
}

// Pass 2: serial combine over chunks -> chunk-start states, IN PLACE over Pc.
__global__ void k_scan2(float* PcH0, const float* __restrict__ Sc) {
    int t = blockIdx.x * blockDim.x + threadIdx.x;
    if (t >= NLANE) return;
    float hs = 0.f;
    for (int c = 0; c < NCH; ++c) {
        size_t ix = (size_t)c * NLANE + t;
        float p = PcH0[ix];
        float s = Sc[ix];
        PcH0[ix] = hs;
        hs = fmaf(p, hs, s);
    }
}

// ================= fused back: scan replay + gate + out-proj + residual =========
// grid (HB, NCH), block 256 = two batch halves x 128 d.
template<bool SAVE_CF>
__global__ __launch_bounds__(256, 8) void k_back(
    const float* __restrict__ XA, const float* __restrict__ XD,
    const float* __restrict__ SZ,
    const float* __restrict__ A_log, const float* __restrict__ dt_w,
    const float* __restrict__ dt_b, const float* __restrict__ Dp,
    const float* __restrict__ H0,          // = Pc after k_scan2
    const float* __restrict__ WQ,          // out_w quad-packed [32][64]xfloat4
    const float* __restrict__ RES,
    float* __restrict__ CF, float* __restrict__ OUT)
{
    __shared__ float lds_xd[2 * CH * 36];
    __shared__ float lds_y[2 * CH * DIv];
    const int t  = threadIdx.x;
    const int bq = blockIdx.x, ch = blockIdx.y;

    for (int f = t; f < 2 * CH * 36; f += 256) {
        int half = f / (CH * 36), r = f % (CH * 36);
        int beff = bq + half * HB;
        lds_xd[f] = XD[((size_t)beff * LSEQ + ch * CH) * 36 + r];
    }
    __syncthreads();

    // ---- scan replay + C-dot + D*x + silu(z) gate ----
    {
        int half = t >> 7, d = t & 127;
        int beff = bq + half * HB;
        float A[DSv];
#pragma unroll
        for (int s = 0; s < DSv; ++s) A[s] = -__expf(A_log[d * DSv + s]);
        float4 dw4 = ((const float4*)dt_w)[d];
        float bb = dt_b[d];
        float Dd = Dp[d];
        float h[DSv];
        size_t ofs = (size_t)ch * NLANE + ((size_t)beff * DIv + d) * DSv;
        const float4* h4 = (const float4*)(H0 + ofs);
#pragma unroll
        for (int q = 0; q < 4; ++q) {
            float4 v = h4[q];
            h[4 * q] = v.x; h[4 * q + 1] = v.y; h[4 * q + 2] = v.z; h[4 * q + 3] = v.w;
        }
        const float* xdh = lds_xd + half * CH * 36;
#pragma unroll
        for (int l = 0; l < CH; ++l) {
            const float* xd = xdh + l * 36;
            float delta = softplusf(fmaf(xd[0], dw4.x, fmaf(xd[1], dw4.y,
                                   fmaf(xd[2], dw4.z, fmaf(xd[3], dw4.w, bb)))));
            size_t base = (size_t)beff * LSEQ + ch * CH + l;
            float x  = XA[base * DIv + d];
            float dx = delta * x;
            float p = 0.f;
#pragma unroll
            for (int s = 0; s < DSv; ++s) {
                float dA = __expf(delta * A[s]);
                h[s] = fmaf(dA, h[s], dx * xd[DRv + s]);
                p = fmaf(h[s], xd[DRv + DSv + s], p);
            }
            float y = fmaf(Dd, x, p);
            lds_y[half * CH * DIv + l * DIv + d] = y * SZ[base * DIv + d];
        }
    }
    __syncthreads();

    // ---- out-proj (q-outer, wq in 4 regs) + 0.5*(cf1+cf2)+res, relu ----
    {
        int e = t & 63, g = t >> 6;     // g = l-group (wave-uniform), 2 l each
        int l0 = g * 2;
        const float4* wq4 = (const float4*)WQ;
        float accA[2] = {0.f, 0.f};
        float accB[2] = {0.f, 0.f};
#pragma unroll
        for (int q = 0; q < DIv / 4; ++q) {
            float4 wq = wq4[q * 64 + e];
#pragma unroll
            for (int i = 0; i < 2; ++i) {
                const float4 y1 = *(const float4*)(lds_y + (l0 + i) * DIv + q * 4);
                const float4 y2 = *(const float4*)(lds_y + CH * DIv + (l0 + i) * DIv + q * 4);
                accA[i] = fmaf(y1.x, wq.x, accA[i]); accA[i] = fmaf(y1.y, wq.y, accA[i]);
                accA[i] = fmaf(y1.z, wq.z, accA[i]); accA[i] = fmaf(y1.w, wq.w, accA[i]);
                accB[i] = fmaf(y2.x, wq.x, accB[i]); accB[i] = fmaf(y2.y, wq.y, accB[i]);
                accB[i] = fmaf(y2.z, wq.z, accB[i]); accB[i] = fmaf(y2.w, wq.w, accB[i]);
            }
        }
#pragma unroll
        for (int i = 0; i < 2; ++i) {
            size_t pos1 = (size_t)bq * LSEQ + ch * CH + l0 + i;
            size_t pos2 = pos1 + (size_t)HB * LSEQ;
            if (SAVE_CF) {
                CF[pos1 * DMv + e] = accA[i];
                CF[pos2 * DMv + e] = accB[i];
            }
            float v = fmaf(0.5f, accA[i] + accB[i], RES[pos1 * DMv + e]);
            OUT[pos1 * DMv + e] = fmaxf(v, 0.f);
        }
    }
}

extern "C" void kernel_launch(void* const* d_in, const int* in_sizes, int n_in,
                              void* d_out, int out_size, void* d_ws, size_t ws_size,
                              hipStream_t stream) {
    const float* Ms_in  = (const float*)d_in[0];
    const float* Pan_in = (const float*)d_in[1];
    const float* pa[9];
    const float* pb[9];
    for (int i = 0; i < 9; ++i) {
        pa[i] = (const float*)d_in[2 + i];
        pb[i] = (const float*)d_in[11 + i];
    }
    float* out    = (float*)d_out;
    float* OutMs  = out;
    float* OutPan = out + (size_t)HB * LSEQ * DMv;

    float* ws = (float*)d_ws;
    size_t o = 0;
    float* CF = ws + o; o += (size_t)NPOS * DMv;
    float* XA = ws + o; o += (size_t)NPOS * DIv;
    float* SZ = ws + o; o += (size_t)NPOS * DIv;
    float* XD = ws + o; o += (size_t)NPOS * 36;
    float* Pc = ws + o; o += (size_t)NCH * NLANE;
    float* Sc = ws + o; o += (size_t)NCH * NLANE;
    float* W2Q  = ws + o; o += (size_t)4 * DMv * 2 * DIv;
    float* XPWT = ws + o; o += (size_t)4 * DIv * 36;
    float* OUTQ = ws + o; o += (size_t)4 * DIv * DMv;

    const int TB = 256;

    // ---- one-time weight repacks (z = path*2 + layer) ----
    {
        dim3 gt1((2 * DIv * DMv + TB - 1) / TB, 1, 4);
        k_quadpack<<<gt1, TB, 0, stream>>>(pa[0], pb[0], 2 * DIv, DMv, W2Q);
        dim3 gt2((36 * DIv + TB - 1) / TB, 1, 4);
        k_transpose<<<gt2, TB, 0, stream>>>(pa[3], pb[3], 36, DIv, XPWT);
        dim3 gt3((DMv * DIv + TB - 1) / TB, 1, 4);
        k_quadpack<<<gt3, TB, 0, stream>>>(pa[8], pb[8], DMv, DIv, OUTQ);
    }

    dim3 gF(BB, NCH);
    dim3 gB(HB, NCH);
    int gS = (NLANE + TB - 1) / TB;

    auto scan_mid = [&]() { k_scan2<<<gS, TB, 0, stream>>>(Pc, Sc); };

    auto cw  = [&](const float* const* P, int L) { return P[1] + (size_t)L * DIv * KCv; };
    auto cb  = [&](const float* const* P, int L) { return P[2] + (size_t)L * DIv; };
    auto dw  = [&](const float* const* P, int L) { return P[4] + (size_t)L * DIv * DRv; };
    auto db  = [&](const float* const* P, int L) { return P[5] + (size_t)L * DIv; };
    auto al  = [&](const float* const* P, int L) { return P[6] + (size_t)L * DIv * DSv; };
    auto dp  = [&](const float* const* P, int L) { return P[7] + (size_t)L * DIv; };

    // ---- path a (updates Ms); z = 0,1 ----
    k_front<1><<<gF, 256, 0, stream>>>(Ms_in, Pan_in, W2Q + (size_t)0 * DMv * 2 * DIv,
                                       cw(pa,0), cb(pa,0), XPWT + (size_t)0 * DIv * 36,
                                       al(pa,0), dw(pa,0), db(pa,0), XA, SZ, XD, Pc, Sc);
    scan_mid();
    k_back<true><<<gB, 256, 0, stream>>>(XA, XD, SZ, al(pa,0), dw(pa,0), db(pa,0), dp(pa,0),
                                         Pc, OUTQ + (size_t)0 * DIv * DMv, Ms_in, CF, OutMs);

    k_front<0><<<gF, 256, 0, stream>>>(CF, nullptr, W2Q + (size_t)1 * DMv * 2 * DIv,
                                       cw(pa,1), cb(pa,1), XPWT + (size_t)1 * DIv * 36,
                                       al(pa,1), dw(pa,1), db(pa,1), XA, SZ, XD, Pc, Sc);
    scan_mid();
    k_back<false><<<gB, 256, 0, stream>>>(XA, XD, SZ, al(pa,1), dw(pa,1), db(pa,1), dp(pa,1),
                                          Pc, OUTQ + (size_t)1 * DIv * DMv, OutMs, nullptr, OutMs);

    // ---- path b (updates Pan); z = 2,3 ----
    k_front<2><<<gF, 256, 0, stream>>>(OutMs, Pan_in, W2Q + (size_t)2 * DMv * 2 * DIv,
                                       cw(pb,0), cb(pb,0), XPWT + (size_t)2 * DIv * 36,
                                       al(pb,0), dw(pb,0), db(pb,0), XA, SZ, XD, Pc, Sc);
    scan_mid();
    k_back<true><<<gB, 256, 0, stream>>>(XA, XD, SZ, al(pb,0), dw(pb,0), db(pb,0), dp(pb,0),
                                         Pc, OUTQ + (size_t)2 * DIv * DMv, Pan_in, CF, OutPan);

    k_front<0><<<gF, 256, 0, stream>>>(CF, nullptr, W2Q + (size_t)3 * DMv * 2 * DIv,
                                       cw(pb,1), cb(pb,1), XPWT + (size_t)3 * DIv * 36,
                                       al(pb,1), dw(pb,1), db(pb,1), XA, SZ, XD, Pc, Sc);
    scan_mid();
    k_back<false><<<gB, 256, 0, stream>>>(XA, XD, SZ, al(pb,1), dw(pb,1), db(pb,1), dp(pb,1),
                                          Pc, OUTQ + (size_t)3 * DIv * DMv, OutPan, nullptr, OutPan);
}

// Round 10
// 386.274 us; speedup vs baseline: 1.0243x; 1.0243x over previous
//
#include <hip/hip_runtime.h>
#include <math.h>

// Problem constants
constexpr int BB   = 8;      // mamba batch (2x half-batch)
constexpr int HB   = 4;      // half batch
constexpr int LSEQ = 2048;   // sequence length
constexpr int DMv  = 64;     // d_model
constexpr int DIv  = 128;    // d_inner
constexpr int DSv  = 16;     // d_state
constexpr int DRv  = 4;      // dt rank
constexpr int KCv  = 4;      // conv kernel
constexpr int NPOS = BB * LSEQ;          // 16384 positions
constexpr int CH   = 16;                 // front chunk length
constexpr int NCH  = LSEQ / CH;          // 128 front chunks
constexpr int CHB  = 8;                  // back / scan sub-chunk length
constexpr int NCH2 = LSEQ / CHB;         // 256 scan chunks
constexpr int NLANE = BB * DIv * DSv;    // 16384 scan lanes
constexpr int NROW = CH + 3;             // 19 rows incl. conv halo

#define DEV static __device__ __forceinline__

DEV float fast_rcp(float v) { return __builtin_amdgcn_rcpf(v); }
DEV float siluf(float v) { return v * fast_rcp(1.0f + __expf(-v)); }
DEV float softplusf(float v) { return (v > 20.0f) ? v : __logf(1.0f + __expf(v)); }

// ---------------- weight repack (once per call) ----------------
// quad-pack: src[e*K + k] -> dst[((k>>2)*E + e)*4 + (k&3)]
__global__ void k_quadpack(const float* __restrict__ Aa, const float* __restrict__ Ab,
                           int E, int K, float* __restrict__ dst) {
    int z = blockIdx.z;
    const float* src = (z < 2) ? (Aa + (size_t)z * E * K) : (Ab + (size_t)(z - 2) * E * K);
    float* d = dst + (size_t)z * E * K;
    int idx = blockIdx.x * blockDim.x + threadIdx.x;
    if (idx >= E * K) return;
    int e = idx / K, k = idx % K;
    d[((size_t)(k >> 2) * E + e) * 4 + (k & 3)] = src[idx];
}

// ================= fused front =================================================
// in-proj(+gather) + conv + x-proj + scan pass 1 (sub-chunk granularity CHB).
// grid (BB, NCH), block 256.
// MODE 0: rows from S1. MODE 1: prep_a gather. MODE 2: prep_b gather.
template<int MODE>
__global__ __launch_bounds__(256, 8) void k_front(
    const float* __restrict__ S1, const float* __restrict__ S2,
    const float* __restrict__ WQ,          // in_w quad-packed [16][256]xfloat4
    const float* __restrict__ conv_w, const float* __restrict__ conv_b,
    const float* __restrict__ XPQ,         // xp_w quad-packed [32][36]xfloat4
    const float* __restrict__ A_log, const float* __restrict__ dt_w,
    const float* __restrict__ dt_b,
    float* __restrict__ XA_g, float* __restrict__ SZ_g, float* __restrict__ XD_g,
    float* __restrict__ Pc, float* __restrict__ Sc)
{
    // LDS: lds_x [19][128] (x rows; rows 0..15 reused as xa); lds_xd [16][36];
    //      lds_w [32][36][4] quad-packed xp_w
    __shared__ float smem[NROW * 128 + CH * 36 + DIv * 36];
    float* lds_x  = smem;                            // 2432 floats
    float* lds_xd = smem + NROW * 128;               // 576
    float* lds_w  = smem + NROW * 128 + CH * 36;     // 4608

    const int t  = threadIdx.x;
    const int b8 = blockIdx.x, ch = blockIdx.y;
    const int c0 = ch * CH;

    // stage quad-packed xp_w into LDS (coalesced; consumed after sync #1)
    for (int f = t; f < DIv * 36; f += 256) lds_w[f] = XPQ[f];

    // ---- phase 1: in-proj GEMV, q-outer, acc[NROW]; rows forced to SGPR ----
    {
        const float* rows[NROW];
#pragma unroll
        for (int i = 0; i < NROW; ++i) {
            int c = c0 - 3 + i;
            if (c < 0) { rows[i] = nullptr; continue; }
            int off, sel = 0;
            if (MODE == 0) {
                off = (b8 * LSEQ + c) * DMv;
            } else {
                int b = b8 & 3;
                bool first = (MODE == 1) ? (c < (LSEQ / 2)) : ((c & 1) == 0);
                bool useS2 = (MODE == 1) ? ((b8 < HB) ? !first : first)
                                         : ((b8 < HB) ? first : !first);
                sel = useS2 ? 1 : 0;
                off = (b * LSEQ + c) * DMv;
            }
            off = __builtin_amdgcn_readfirstlane(off);
            sel = __builtin_amdgcn_readfirstlane(sel);
            rows[i] = (sel ? S2 : S1) + off;
        }
        float acc[NROW];
#pragma unroll
        for (int i = 0; i < NROW; ++i) acc[i] = 0.f;
        const float4* wq4 = (const float4*)WQ;
#pragma unroll
        for (int q = 0; q < DMv / 4; ++q) {
            float4 wv = wq4[q * 256 + t];
#pragma unroll
            for (int i = 0; i < NROW; ++i) {
                if (rows[i]) {
                    float4 v = ((const float4*)rows[i])[q];
                    acc[i] = fmaf(v.x, wv.x, acc[i]);
                    acc[i] = fmaf(v.y, wv.y, acc[i]);
                    acc[i] = fmaf(v.z, wv.z, acc[i]);
                    acc[i] = fmaf(v.w, wv.w, acc[i]);
                }
            }
        }
        if (t < DIv) {
#pragma unroll
            for (int i = 0; i < NROW; ++i) lds_x[i * 128 + t] = acc[i];
        } else {
#pragma unroll
            for (int i = 3; i < NROW; ++i)
                SZ_g[((size_t)b8 * LSEQ + (c0 - 3 + i)) * DIv + (t - DIv)] = siluf(acc[i]);
        }
    }
    __syncthreads();

    // ---- phase 2a: causal conv (K=4) + silu into regs ----
    float xar[8];
    {
        const int d = t & 127;
        const int lb = t >> 7;   // 0/1
        float4 cw4 = ((const float4*)conv_w)[d];
        float cb = conv_b[d];
#pragma unroll
        for (int j = 0; j < 8; ++j) {
            int l = lb * 8 + j;
            float a = cb;
            a = fmaf(cw4.x, lds_x[(l + 0) * 128 + d], a);
            a = fmaf(cw4.y, lds_x[(l + 1) * 128 + d], a);
            a = fmaf(cw4.z, lds_x[(l + 2) * 128 + d], a);
            a = fmaf(cw4.w, lds_x[(l + 3) * 128 + d], a);
            float v = siluf(a);
            xar[j] = v;
            XA_g[((size_t)b8 * LSEQ + c0 + l) * DIv + d] = v;
        }
    }
    __syncthreads();
    // ---- phase 2b: write xa into lds_x rows 0..15 (x rows dead) ----
    {
        const int d = t & 127;
        const int lb = t >> 7;
#pragma unroll
        for (int j = 0; j < 8; ++j) lds_x[(lb * 8 + j) * 128 + d] = xar[j];
    }
    __syncthreads();

    // ---- phase 3: x-proj (36 outputs per position), all-b128 LDS reads ----
    for (int f = t; f < CH * 36; f += 256) {
        int l = f / 36, e = f % 36;
        const float4* x4 = (const float4*)(lds_x + l * 128);
        const float4* w4 = (const float4*)lds_w;
        float a0 = 0.f, a1 = 0.f;
#pragma unroll
        for (int q = 0; q < DIv / 4; q += 2) {
            float4 xv0 = x4[q],           wv0 = w4[q * 36 + e];
            float4 xv1 = x4[q + 1],       wv1 = w4[(q + 1) * 36 + e];
            a0 = fmaf(xv0.x, wv0.x, a0); a0 = fmaf(xv0.y, wv0.y, a0);
            a0 = fmaf(xv0.z, wv0.z, a0); a0 = fmaf(xv0.w, wv0.w, a0);
            a1 = fmaf(xv1.x, wv1.x, a1); a1 = fmaf(xv1.y, wv1.y, a1);
            a1 = fmaf(xv1.z, wv1.z, a1); a1 = fmaf(xv1.w, wv1.w, a1);
        }
        float v = a0 + a1;
        lds_xd[f] = v;
        XD_g[((size_t)b8 * LSEQ + c0) * 36 + f] = v;
    }
    __syncthreads();

    // ---- phase 4: scan pass 1 at sub-chunk CHB, b128 xd reads ----
    {
        int d = t & 127, sh = t >> 7;
        float A[8];
#pragma unroll
        for (int s = 0; s < 8; ++s) A[s] = -__expf(A_log[d * DSv + sh * 8 + s]);
        float4 dw4 = ((const float4*)dt_w)[d];
        float bb = dt_b[d];
#pragma unroll
        for (int half = 0; half < 2; ++half) {
            float h[8], P[8];
#pragma unroll
            for (int s = 0; s < 8; ++s) { h[s] = 0.f; P[s] = 1.f; }
#pragma unroll
            for (int j = 0; j < CHB; ++j) {
                int l = half * CHB + j;
                const float* xdl = lds_xd + l * 36;
                float4 dt4 = *(const float4*)xdl;
                float delta = softplusf(fmaf(dt4.x, dw4.x, fmaf(dt4.y, dw4.y,
                                       fmaf(dt4.z, dw4.z, fmaf(dt4.w, dw4.w, bb)))));
                float dx = delta * lds_x[l * 128 + d];
                float4 b0 = *(const float4*)(xdl + 4 + sh * 8);
                float4 b1 = *(const float4*)(xdl + 8 + sh * 8);
                float bv[8] = {b0.x, b0.y, b0.z, b0.w, b1.x, b1.y, b1.z, b1.w};
#pragma unroll
                for (int s = 0; s < 8; ++s) {
                    float dA = __expf(delta * A[s]);
                    h[s] = fmaf(dA, h[s], dx * bv[s]);
                    P[s] *= dA;
                }
            }
            size_t c2 = (size_t)(ch * 2 + half);
            size_t ofs = c2 * NLANE + ((size_t)b8 * DIv + d) * DSv + sh * 8;
            float4* p4 = (float4*)(Pc + ofs);
            float4* s4 = (float4*)(Sc + ofs);
            p4[0] = make_float4(P[0], P[1], P[2], P[3]);
            p4[1] = make_float4(P[4], P[5], P[6], P[7]);
            s4[0] = make_float4(h[0], h[1], h[2], h[3]);
            s4[1] = make_float4(h[4], h[5], h[6], h[7]);
        }
    }
}

// Pass 2: serial combine over NCH2 chunks -> chunk-start states, IN PLACE over Pc.
__global__ void k_scan2(float* PcH0, const float* __restrict__ Sc) {
    int t = blockIdx.x * blockDim.x + threadIdx.x;
    if (t >= NLANE) return;
    float hs = 0.f;
    for (int c = 0; c < NCH2; ++c) {
        size_t ix = (size_t)c * NLANE + t;
        float p = PcH0[ix];
        float s = Sc[ix];
        PcH0[ix] = hs;
        hs = fmaf(p, hs, s);
    }
}

// ================= fused back: scan replay + gate + out-proj + residual =========
// grid (HB, NCH2), block 256 = two batch halves x 128 d. Chunk of CHB=8.
template<bool SAVE_CF>
__global__ __launch_bounds__(256, 8) void k_back(
    const float* __restrict__ XA, const float* __restrict__ XD,
    const float* __restrict__ SZ,
    const float* __restrict__ A_log, const float* __restrict__ dt_w,
    const float* __restrict__ dt_b, const float* __restrict__ Dp,
    const float* __restrict__ H0,          // = Pc after k_scan2
    const float* __restrict__ WQ,          // out_w quad-packed [32][64]xfloat4
    const float* __restrict__ RES,
    float* __restrict__ CF, float* __restrict__ OUT)
{
    __shared__ float lds_xd[2 * CHB * 36];
    __shared__ float lds_y[2 * CHB * DIv];
    const int t  = threadIdx.x;
    const int bq = blockIdx.x, ch = blockIdx.y;

    for (int f = t; f < 2 * CHB * 36; f += 256) {
        int half = f / (CHB * 36), r = f % (CHB * 36);
        int beff = bq + half * HB;
        lds_xd[f] = XD[((size_t)beff * LSEQ + ch * CHB) * 36 + r];
    }
    __syncthreads();

    // ---- scan replay + C-dot + D*x + silu(z) gate (b128 xd reads) ----
    {
        int half = t >> 7, d = t & 127;
        int beff = bq + half * HB;
        float A[DSv];
#pragma unroll
        for (int s = 0; s < DSv; ++s) A[s] = -__expf(A_log[d * DSv + s]);
        float4 dw4 = ((const float4*)dt_w)[d];
        float bb = dt_b[d];
        float Dd = Dp[d];
        float h[DSv];
        size_t ofs = (size_t)ch * NLANE + ((size_t)beff * DIv + d) * DSv;
        const float4* h4 = (const float4*)(H0 + ofs);
#pragma unroll
        for (int q = 0; q < 4; ++q) {
            float4 v = h4[q];
            h[4 * q] = v.x; h[4 * q + 1] = v.y; h[4 * q + 2] = v.z; h[4 * q + 3] = v.w;
        }
        const float* xdh = lds_xd + half * CHB * 36;
#pragma unroll
        for (int l = 0; l < CHB; ++l) {
            const float* xdl = xdh + l * 36;
            float4 dt4 = *(const float4*)xdl;
            float delta = softplusf(fmaf(dt4.x, dw4.x, fmaf(dt4.y, dw4.y,
                                   fmaf(dt4.z, dw4.z, fmaf(dt4.w, dw4.w, bb)))));
            size_t base = (size_t)beff * LSEQ + ch * CHB + l;
            float x  = XA[base * DIv + d];
            float dx = delta * x;
            float4 B0 = *(const float4*)(xdl + 4);
            float4 B1 = *(const float4*)(xdl + 8);
            float4 B2 = *(const float4*)(xdl + 12);
            float4 B3 = *(const float4*)(xdl + 16);
            float4 C0 = *(const float4*)(xdl + 20);
            float4 C1 = *(const float4*)(xdl + 24);
            float4 C2 = *(const float4*)(xdl + 28);
            float4 C3 = *(const float4*)(xdl + 32);
            float bv[16] = {B0.x,B0.y,B0.z,B0.w, B1.x,B1.y,B1.z,B1.w,
                            B2.x,B2.y,B2.z,B2.w, B3.x,B3.y,B3.z,B3.w};
            float cv[16] = {C0.x,C0.y,C0.z,C0.w, C1.x,C1.y,C1.z,C1.w,
                            C2.x,C2.y,C2.z,C2.w, C3.x,C3.y,C3.z,C3.w};
            float p = 0.f;
#pragma unroll
            for (int s = 0; s < DSv; ++s) {
                float dA = __expf(delta * A[s]);
                h[s] = fmaf(dA, h[s], dx * bv[s]);
                p = fmaf(h[s], cv[s], p);
            }
            float y = fmaf(Dd, x, p);
            lds_y[half * CHB * DIv + l * DIv + d] = y * SZ[base * DIv + d];
        }
    }
    __syncthreads();

    // ---- out-proj (q-outer, wq in 4 regs) + 0.5*(cf1+cf2)+res, relu ----
    {
        int e = t & 63, g = t >> 6;     // g = l-group (wave-uniform), 2 l each
        int l0 = g * 2;
        const float4* wq4 = (const float4*)WQ;
        float accA[2] = {0.f, 0.f};
        float accB[2] = {0.f, 0.f};
#pragma unroll
        for (int q = 0; q < DIv / 4; ++q) {
            float4 wq = wq4[q * 64 + e];
#pragma unroll
            for (int i = 0; i < 2; ++i) {
                const float4 y1 = *(const float4*)(lds_y + (l0 + i) * DIv + q * 4);
                const float4 y2 = *(const float4*)(lds_y + CHB * DIv + (l0 + i) * DIv + q * 4);
                accA[i] = fmaf(y1.x, wq.x, accA[i]); accA[i] = fmaf(y1.y, wq.y, accA[i]);
                accA[i] = fmaf(y1.z, wq.z, accA[i]); accA[i] = fmaf(y1.w, wq.w, accA[i]);
                accB[i] = fmaf(y2.x, wq.x, accB[i]); accB[i] = fmaf(y2.y, wq.y, accB[i]);
                accB[i] = fmaf(y2.z, wq.z, accB[i]); accB[i] = fmaf(y2.w, wq.w, accB[i]);
            }
        }
#pragma unroll
        for (int i = 0; i < 2; ++i) {
            size_t pos1 = (size_t)bq * LSEQ + ch * CHB + l0 + i;
            size_t pos2 = pos1 + (size_t)HB * LSEQ;
            if (SAVE_CF) {
                CF[pos1 * DMv + e] = accA[i];
                CF[pos2 * DMv + e] = accB[i];
            }
            float v = fmaf(0.5f, accA[i] + accB[i], RES[pos1 * DMv + e]);
            OUT[pos1 * DMv + e] = fmaxf(v, 0.f);
        }
    }
}

extern "C" void kernel_launch(void* const* d_in, const int* in_sizes, int n_in,
                              void* d_out, int out_size, void* d_ws, size_t ws_size,
                              hipStream_t stream) {
    const float* Ms_in  = (const float*)d_in[0];
    const float* Pan_in = (const float*)d_in[1];
    const float* pa[9];
    const float* pb[9];
    for (int i = 0; i < 9; ++i) {
        pa[i] = (const float*)d_in[2 + i];
        pb[i] = (const float*)d_in[11 + i];
    }
    float* out    = (float*)d_out;
    float* OutMs  = out;
    float* OutPan = out + (size_t)HB * LSEQ * DMv;

    float* ws = (float*)d_ws;
    size_t o = 0;
    float* CF = ws + o; o += (size_t)NPOS * DMv;
    float* XA = ws + o; o += (size_t)NPOS * DIv;
    float* SZ = ws + o; o += (size_t)NPOS * DIv;
    float* XD = ws + o; o += (size_t)NPOS * 36;
    float* Pc = ws + o; o += (size_t)NCH2 * NLANE;
    float* Sc = ws + o; o += (size_t)NCH2 * NLANE;
    float* W2Q  = ws + o; o += (size_t)4 * DMv * 2 * DIv;   // in_w quad-packed
    float* XPQ  = ws + o; o += (size_t)4 * DIv * 36;        // xp_w quad-packed
    float* OUTQ = ws + o; o += (size_t)4 * DIv * DMv;       // out_w quad-packed

    const int TB = 256;

    // ---- one-time weight repacks (z = path*2 + layer) ----
    {
        dim3 gt1((2 * DIv * DMv + TB - 1) / TB, 1, 4);
        k_quadpack<<<gt1, TB, 0, stream>>>(pa[0], pb[0], 2 * DIv, DMv, W2Q);
        dim3 gt2((36 * DIv + TB - 1) / TB, 1, 4);
        k_quadpack<<<gt2, TB, 0, stream>>>(pa[3], pb[3], 36, DIv, XPQ);
        dim3 gt3((DMv * DIv + TB - 1) / TB, 1, 4);
        k_quadpack<<<gt3, TB, 0, stream>>>(pa[8], pb[8], DMv, DIv, OUTQ);
    }

    dim3 gF(BB, NCH);
    dim3 gB(HB, NCH2);
    int gS = (NLANE + TB - 1) / TB;

    auto scan_mid = [&]() { k_scan2<<<gS, TB, 0, stream>>>(Pc, Sc); };

    auto cw  = [&](const float* const* P, int L) { return P[1] + (size_t)L * DIv * KCv; };
    auto cb  = [&](const float* const* P, int L) { return P[2] + (size_t)L * DIv; };
    auto dw  = [&](const float* const* P, int L) { return P[4] + (size_t)L * DIv * DRv; };
    auto db  = [&](const float* const* P, int L) { return P[5] + (size_t)L * DIv; };
    auto al  = [&](const float* const* P, int L) { return P[6] + (size_t)L * DIv * DSv; };
    auto dp  = [&](const float* const* P, int L) { return P[7] + (size_t)L * DIv; };

    // ---- path a (updates Ms); z = 0,1 ----
    k_front<1><<<gF, 256, 0, stream>>>(Ms_in, Pan_in, W2Q + (size_t)0 * DMv * 2 * DIv,
                                       cw(pa,0), cb(pa,0), XPQ + (size_t)0 * DIv * 36,
                                       al(pa,0), dw(pa,0), db(pa,0), XA, SZ, XD, Pc, Sc);
    scan_mid();
    k_back<true><<<gB, 256, 0, stream>>>(XA, XD, SZ, al(pa,0), dw(pa,0), db(pa,0), dp(pa,0),
                                         Pc, OUTQ + (size_t)0 * DIv * DMv, Ms_in, CF, OutMs);

    k_front<0><<<gF, 256, 0, stream>>>(CF, nullptr, W2Q + (size_t)1 * DMv * 2 * DIv,
                                       cw(pa,1), cb(pa,1), XPQ + (size_t)1 * DIv * 36,
                                       al(pa,1), dw(pa,1), db(pa,1), XA, SZ, XD, Pc, Sc);
    scan_mid();
    k_back<false><<<gB, 256, 0, stream>>>(XA, XD, SZ, al(pa,1), dw(pa,1), db(pa,1), dp(pa,1),
                                          Pc, OUTQ + (size_t)1 * DIv * DMv, OutMs, nullptr, OutMs);

    // ---- path b (updates Pan); z = 2,3 ----
    k_front<2><<<gF, 256, 0, stream>>>(OutMs, Pan_in, W2Q + (size_t)2 * DMv * 2 * DIv,
                                       cw(pb,0), cb(pb,0), XPQ + (size_t)2 * DIv * 36,
                                       al(pb,0), dw(pb,0), db(pb,0), XA, SZ, XD, Pc, Sc);
    scan_mid();
    k_back<true><<<gB, 256, 0, stream>>>(XA, XD, SZ, al(pb,0), dw(pb,0), db(pb,0), dp(pb,0),
                                         Pc, OUTQ + (size_t)2 * DIv * DMv, Pan_in, CF, OutPan);

    k_front<0><<<gF, 256, 0, stream>>>(CF, nullptr, W2Q + (size_t)3 * DMv * 2 * DIv,
                                       cw(pb,1), cb(pb,1), XPQ + (size_t)3 * DIv * 36,
                                       al(pb,1), dw(pb,1), db(pb,1), XA, SZ, XD, Pc, Sc);
    scan_mid();
    k_back<false><<<gB, 256, 0, stream>>>(XA, XD, SZ, al(pb,1), dw(pb,1), db(pb,1), dp(pb,1),
                                          Pc, OUTQ + (size_t)3 * DIv * DMv, OutPan, nullptr, OutPan);
}